// Round 1
// baseline (679.829 us; speedup 1.0000x reference)
//
#include <hip/hip_runtime.h>
#include <math.h>

#define N_NODES 100000
#define N_EDGES 1600000
#define FIN 256
#define HDIM 64
#define CDIM 16

// ---------------- degree ----------------
__global__ void k_count_deg(const int* __restrict__ dst, float* __restrict__ deg) {
    int e = blockIdx.x * blockDim.x + threadIdx.x;
    if (e < N_EDGES) atomicAdd(&deg[dst[e]], 1.0f);
}

__global__ void k_dinv(float* __restrict__ deg) {
    int i = blockIdx.x * blockDim.x + threadIdx.x;
    if (i < N_NODES) deg[i] = rsqrtf(deg[i] + 1.0f);  // +1 = self loop
}

// ---------------- GEMM1: h = x @ W1  (N x 256 @ 256 x 64) ----------------
// W1 transposed in LDS as [c][k], XOR-swizzled float4 quads (bank-optimal, no pad).
// 256 threads: c = tid&63, rg = tid>>6 picks 4 rows. 64 rows/block, 4 passes of 16 rows.
__global__ __launch_bounds__(256) void k_gemm1(const float* __restrict__ x,
                                               const float* __restrict__ W1,
                                               float* __restrict__ h) {
    __shared__ float W1t[64][FIN];   // 64 KB, [c][swizzled k]
    __shared__ float xs[16][FIN];    // 16 KB
    const int tid = threadIdx.x;
    const int c = tid & 63;
    const int rg = tid >> 6;         // 0..3
    const int cs = c & 7;            // swizzle key

    // load W1 [k][c] -> W1t[c][swz(k)]
    for (int i = tid; i < FIN * 64; i += 256) {
        int k = i >> 6, cc = i & 63;
        int kq = k >> 2, j = k & 3;
        W1t[cc][(((kq ^ (cc & 7)) << 2) | j)] = W1[i];
    }

    const int row0 = blockIdx.x * 64;
    for (int rr = 0; rr < 64; rr += 16) {
        __syncthreads();
        // stage 16 rows of x (16*256 floats = 1024 float4, 4 per thread)
        for (int i = tid; i < 16 * 64; i += 256) {
            int r = i >> 6;      // 0..15
            int q = i & 63;      // float4 index within row
            int row = row0 + rr + r;
            float4 v = make_float4(0.f, 0.f, 0.f, 0.f);
            if (row < N_NODES) v = ((const float4*)x)[(size_t)row * 64 + q];
            *(float4*)&xs[r][q * 4] = v;
        }
        __syncthreads();

        float acc0 = 0.f, acc1 = 0.f, acc2 = 0.f, acc3 = 0.f;
        const float* w_row = &W1t[c][0];
        const float* x0r = &xs[rg * 4 + 0][0];
        const float* x1r = &xs[rg * 4 + 1][0];
        const float* x2r = &xs[rg * 4 + 2][0];
        const float* x3r = &xs[rg * 4 + 3][0];
        #pragma unroll 8
        for (int kq = 0; kq < 64; ++kq) {
            float4 w = *(const float4*)&w_row[(kq ^ cs) << 2];
            float4 a0 = *(const float4*)&x0r[kq << 2];
            float4 a1 = *(const float4*)&x1r[kq << 2];
            float4 a2 = *(const float4*)&x2r[kq << 2];
            float4 a3 = *(const float4*)&x3r[kq << 2];
            acc0 = fmaf(w.x, a0.x, fmaf(w.y, a0.y, fmaf(w.z, a0.z, fmaf(w.w, a0.w, acc0))));
            acc1 = fmaf(w.x, a1.x, fmaf(w.y, a1.y, fmaf(w.z, a1.z, fmaf(w.w, a1.w, acc1))));
            acc2 = fmaf(w.x, a2.x, fmaf(w.y, a2.y, fmaf(w.z, a2.z, fmaf(w.w, a2.w, acc2))));
            acc3 = fmaf(w.x, a3.x, fmaf(w.y, a3.y, fmaf(w.z, a3.z, fmaf(w.w, a3.w, acc3))));
        }
        int row = row0 + rr + rg * 4;
        if (row + 0 < N_NODES) h[(size_t)(row + 0) * 64 + c] = acc0;
        if (row + 1 < N_NODES) h[(size_t)(row + 1) * 64 + c] = acc1;
        if (row + 2 < N_NODES) h[(size_t)(row + 2) * 64 + c] = acc2;
        if (row + 3 < N_NODES) h[(size_t)(row + 3) * 64 + c] = acc3;
    }
}

// ---------------- scatter layer 1: agg1[dst] += h[src] * norm ----------------
// one 64-lane wave per edge, lane = channel
__global__ __launch_bounds__(256) void k_scatter1(const int* __restrict__ src,
                                                  const int* __restrict__ dst,
                                                  const float* __restrict__ dinv,
                                                  const float* __restrict__ h,
                                                  float* __restrict__ agg1) {
    int e = blockIdx.x * 4 + (threadIdx.x >> 6);
    if (e >= N_EDGES) return;
    int s = src[e], d = dst[e];
    float nrm = dinv[s] * dinv[d];
    int c = threadIdx.x & 63;
    atomicAdd(&agg1[(size_t)d * 64 + c], h[(size_t)s * 64 + c] * nrm);
}

// ---------------- fused: h1 = relu(agg1 + h*dinv^2 + b1); h2 = h1 @ W2 ----------------
__global__ __launch_bounds__(256) void k_epi1_gemm2(const float* __restrict__ agg1,
                                                    const float* __restrict__ h,
                                                    const float* __restrict__ dinv,
                                                    const float* __restrict__ b1,
                                                    const float* __restrict__ W2,
                                                    float* __restrict__ h2) {
    __shared__ float h1s[16][65];
    __shared__ float W2s[64][17];
    int tid = threadIdx.x;
    for (int i = tid; i < 64 * 16; i += 256) W2s[i >> 4][i & 15] = W2[i];
    int row0 = blockIdx.x * 16;
    for (int i = tid; i < 16 * 64; i += 256) {
        int r = i >> 6, cc = i & 63;
        int row = row0 + r;
        float v = 0.f;
        if (row < N_NODES) {
            float di = dinv[row];
            v = agg1[(size_t)row * 64 + cc] + h[(size_t)row * 64 + cc] * di * di + b1[cc];
        }
        h1s[r][cc] = fmaxf(v, 0.f);
    }
    __syncthreads();
    int r = tid >> 4, cc = tid & 15;
    float acc = 0.f;
    #pragma unroll
    for (int k = 0; k < 64; ++k) acc = fmaf(h1s[r][k], W2s[k][cc], acc);
    int row = row0 + r;
    if (row < N_NODES) h2[(size_t)row * 16 + cc] = acc;  // bias b2 added after aggregation
}

// ---------------- scatter layer 2 ----------------
__global__ __launch_bounds__(256) void k_scatter2(const int* __restrict__ src,
                                                  const int* __restrict__ dst,
                                                  const float* __restrict__ dinv,
                                                  const float* __restrict__ h2,
                                                  float* __restrict__ agg2) {
    int e = blockIdx.x * 16 + (threadIdx.x >> 4);
    if (e >= N_EDGES) return;
    int s = src[e], d = dst[e];
    float nrm = dinv[s] * dinv[d];
    int c = threadIdx.x & 15;
    atomicAdd(&agg2[(size_t)d * 16 + c], h2[(size_t)s * 16 + c] * nrm);
}

// ---------------- final: z = agg2 + h2*dinv^2 + b2 ; log_softmax over 16 ----------------
__global__ __launch_bounds__(256) void k_final(const float* __restrict__ agg2,
                                               const float* __restrict__ h2,
                                               const float* __restrict__ dinv,
                                               const float* __restrict__ b2,
                                               float* __restrict__ out) {
    int tid = threadIdx.x;
    int row = blockIdx.x * 16 + (tid >> 4);
    int c = tid & 15;
    if (row >= N_NODES) return;
    float di = dinv[row];
    float z = agg2[(size_t)row * 16 + c] + h2[(size_t)row * 16 + c] * di * di + b2[c];
    float m = z;
    #pragma unroll
    for (int off = 8; off >= 1; off >>= 1) m = fmaxf(m, __shfl_xor(m, off, 16));
    float ex = __expf(z - m);
    float s = ex;
    #pragma unroll
    for (int off = 8; off >= 1; off >>= 1) s += __shfl_xor(s, off, 16);
    out[(size_t)row * 16 + c] = z - m - logf(s);
}

extern "C" void kernel_launch(void* const* d_in, const int* in_sizes, int n_in,
                              void* d_out, int out_size, void* d_ws, size_t ws_size,
                              hipStream_t stream) {
    const float* x  = (const float*)d_in[0];
    const int* ei   = (const int*)d_in[1];
    const float* W1 = (const float*)d_in[2];
    const float* b1 = (const float*)d_in[3];
    const float* W2 = (const float*)d_in[4];
    const float* b2 = (const float*)d_in[5];
    const int* src = ei;              // edge_index[0]
    const int* dst = ei + N_EDGES;    // edge_index[1]

    float* ws   = (float*)d_ws;
    float* agg1 = ws;                                   // N*64
    float* agg2 = agg1 + (size_t)N_NODES * 64;          // N*16
    float* dinv = agg2 + (size_t)N_NODES * 16;          // N (deg then dinv, in place)
    float* h    = dinv + N_NODES;                       // N*64
    float* h2   = h + (size_t)N_NODES * 64;             // N*16
    float* out  = (float*)d_out;

    // zero agg1 | agg2 | deg (contiguous)
    hipMemsetAsync(agg1, 0,
        ((size_t)N_NODES * 64 + (size_t)N_NODES * 16 + N_NODES) * sizeof(float), stream);

    k_count_deg<<<(N_EDGES + 255) / 256, 256, 0, stream>>>(dst, dinv);
    k_dinv<<<(N_NODES + 255) / 256, 256, 0, stream>>>(dinv);
    k_gemm1<<<(N_NODES + 63) / 64, 256, 0, stream>>>(x, W1, h);
    k_scatter1<<<(N_EDGES + 3) / 4, 256, 0, stream>>>(src, dst, dinv, h, agg1);
    k_epi1_gemm2<<<(N_NODES + 15) / 16, 256, 0, stream>>>(agg1, h, dinv, b1, W2, h2);
    k_scatter2<<<(N_EDGES + 15) / 16, 256, 0, stream>>>(src, dst, dinv, h2, agg2);
    k_final<<<(N_NODES + 15) / 16, 256, 0, stream>>>(agg2, h2, dinv, b2, out);
}

// Round 2
// 499.122 us; speedup vs baseline: 1.3620x; 1.3620x over previous
//
#include <hip/hip_runtime.h>
#include <math.h>

#define N_NODES 100000
#define N_EDGES 1600000
#define FIN 256
#define NBLK_NODES 391   // ceil(100000/256)

// ---------------- degree (int) ----------------
__global__ __launch_bounds__(256) void k_count_deg(const int* __restrict__ dst, int* __restrict__ degi) {
    int e = blockIdx.x * 256 + threadIdx.x;
    if (e < N_EDGES) atomicAdd(&degi[dst[e]], 1);
}

__global__ __launch_bounds__(256) void k_dinv(const int* __restrict__ degi, float* __restrict__ dinv) {
    int i = blockIdx.x * 256 + threadIdx.x;
    if (i < N_NODES) dinv[i] = rsqrtf((float)degi[i] + 1.0f);  // +1 = self loop
}

// ---------------- CSR build: 2-level exclusive scan ----------------
__global__ __launch_bounds__(256) void k_block_sum(const int* __restrict__ degi, int* __restrict__ bsums) {
    __shared__ int sd[256];
    int tid = threadIdx.x;
    int i = blockIdx.x * 256 + tid;
    sd[tid] = (i < N_NODES) ? degi[i] : 0;
    __syncthreads();
    for (int s = 128; s > 0; s >>= 1) {
        if (tid < s) sd[tid] += sd[tid + s];
        __syncthreads();
    }
    if (tid == 0) bsums[blockIdx.x] = sd[0];
}

__global__ __launch_bounds__(512) void k_scan_bsums(int* __restrict__ bsums, int nb) {
    __shared__ int sd[512];
    int tid = threadIdx.x;
    int v = (tid < nb) ? bsums[tid] : 0;
    sd[tid] = v;
    __syncthreads();
    for (int off = 1; off < 512; off <<= 1) {
        int t = (tid >= off) ? sd[tid - off] : 0;
        __syncthreads();
        sd[tid] += t;
        __syncthreads();
    }
    if (tid < nb) bsums[tid] = sd[tid] - v;  // exclusive
}

__global__ __launch_bounds__(256) void k_scan_block(const int* __restrict__ degi,
                                                   const int* __restrict__ bsums,
                                                   int* __restrict__ offsets) {
    __shared__ int sd[256];
    int tid = threadIdx.x;
    int i = blockIdx.x * 256 + tid;
    int v = (i < N_NODES) ? degi[i] : 0;
    sd[tid] = v;
    __syncthreads();
    for (int off = 1; off < 256; off <<= 1) {
        int t = (tid >= off) ? sd[tid - off] : 0;
        __syncthreads();
        sd[tid] += t;
        __syncthreads();
    }
    if (i < N_NODES) offsets[i] = bsums[blockIdx.x] + sd[tid] - v;
    if (i == N_NODES - 1) offsets[N_NODES] = bsums[blockIdx.x] + sd[tid];
}

// ---------------- fill CSR slots: pack = {src, norm} ----------------
__global__ __launch_bounds__(256) void k_fill(const int* __restrict__ src, const int* __restrict__ dst,
                                              const float* __restrict__ dinv,
                                              const int* __restrict__ offsets, int* __restrict__ cursor,
                                              int2* __restrict__ pack) {
    int e = blockIdx.x * 256 + threadIdx.x;
    if (e >= N_EDGES) return;
    int s = src[e], d = dst[e];
    int pos = offsets[d] + atomicAdd(&cursor[d], 1);
    pack[pos] = make_int2(s, __float_as_int(dinv[s] * dinv[d]));
}

// ---------------- GEMM1: h = x @ W1  (N x 256 @ 256 x 64) ----------------
__global__ __launch_bounds__(256) void k_gemm1(const float* __restrict__ x,
                                               const float* __restrict__ W1,
                                               float* __restrict__ h) {
    __shared__ float W1t[64][FIN];   // [c][swizzled k]
    __shared__ float xs[16][FIN];
    const int tid = threadIdx.x;
    const int c = tid & 63;
    const int rg = tid >> 6;
    const int cs = c & 7;

    for (int i = tid; i < FIN * 64; i += 256) {
        int k = i >> 6, cc = i & 63;
        int kq = k >> 2, j = k & 3;
        W1t[cc][(((kq ^ (cc & 7)) << 2) | j)] = W1[i];
    }

    const int row0 = blockIdx.x * 64;
    for (int rr = 0; rr < 64; rr += 16) {
        __syncthreads();
        for (int i = tid; i < 16 * 64; i += 256) {
            int r = i >> 6;
            int q = i & 63;
            int row = row0 + rr + r;
            float4 v = make_float4(0.f, 0.f, 0.f, 0.f);
            if (row < N_NODES) v = ((const float4*)x)[(size_t)row * 64 + q];
            *(float4*)&xs[r][q * 4] = v;
        }
        __syncthreads();

        float acc0 = 0.f, acc1 = 0.f, acc2 = 0.f, acc3 = 0.f;
        const float* w_row = &W1t[c][0];
        const float* x0r = &xs[rg * 4 + 0][0];
        const float* x1r = &xs[rg * 4 + 1][0];
        const float* x2r = &xs[rg * 4 + 2][0];
        const float* x3r = &xs[rg * 4 + 3][0];
        #pragma unroll 8
        for (int kq = 0; kq < 64; ++kq) {
            float4 w = *(const float4*)&w_row[(kq ^ cs) << 2];
            float4 a0 = *(const float4*)&x0r[kq << 2];
            float4 a1 = *(const float4*)&x1r[kq << 2];
            float4 a2 = *(const float4*)&x2r[kq << 2];
            float4 a3 = *(const float4*)&x3r[kq << 2];
            acc0 = fmaf(w.x, a0.x, fmaf(w.y, a0.y, fmaf(w.z, a0.z, fmaf(w.w, a0.w, acc0))));
            acc1 = fmaf(w.x, a1.x, fmaf(w.y, a1.y, fmaf(w.z, a1.z, fmaf(w.w, a1.w, acc1))));
            acc2 = fmaf(w.x, a2.x, fmaf(w.y, a2.y, fmaf(w.z, a2.z, fmaf(w.w, a2.w, acc2))));
            acc3 = fmaf(w.x, a3.x, fmaf(w.y, a3.y, fmaf(w.z, a3.z, fmaf(w.w, a3.w, acc3))));
        }
        int row = row0 + rr + rg * 4;
        if (row + 0 < N_NODES) h[(size_t)(row + 0) * 64 + c] = acc0;
        if (row + 1 < N_NODES) h[(size_t)(row + 1) * 64 + c] = acc1;
        if (row + 2 < N_NODES) h[(size_t)(row + 2) * 64 + c] = acc2;
        if (row + 3 < N_NODES) h[(size_t)(row + 3) * 64 + c] = acc3;
    }
}

// ---------------- fused agg1 + self-loop + b1 + relu + GEMM2 ----------------
// one 64-lane wave per node; 4 nodes per block. N_NODES % 4 == 0 -> no divergent barrier.
__global__ __launch_bounds__(256) void k_agg1_gemm2(const int* __restrict__ offsets,
                                                    const int2* __restrict__ pack,
                                                    const float* __restrict__ dinv,
                                                    const float* __restrict__ h,
                                                    const float* __restrict__ b1,
                                                    const float* __restrict__ W2,
                                                    float* __restrict__ h2) {
    __shared__ float W2s[64][17];
    __shared__ float h1s[4][64];
    const int tid = threadIdx.x;
    for (int i = tid; i < 64 * 16; i += 256) W2s[i >> 4][i & 15] = W2[i];
    __syncthreads();

    const int wave = tid >> 6;
    const int lane = tid & 63;
    const int node = blockIdx.x * 4 + wave;

    const float di = dinv[node];
    float acc = h[(size_t)node * 64 + lane] * di * di;   // self loop
    const int s0 = offsets[node], s1 = offsets[node + 1];
    for (int i = s0; i < s1; ++i) {
        int2 p = pack[i];
        acc = fmaf(h[(size_t)p.x * 64 + lane], __int_as_float(p.y), acc);
    }
    acc = fmaxf(acc + b1[lane], 0.f);
    h1s[wave][lane] = acc;   // same-wave LDS write->read: ordered via lgkmcnt

    const int j = lane >> 4, cc = lane & 15;
    float a2 = 0.f;
    #pragma unroll
    for (int t = 0; t < 16; ++t) {
        int k = j * 16 + t;
        a2 = fmaf(h1s[wave][k], W2s[k][cc], a2);
    }
    a2 += __shfl_xor(a2, 16);
    a2 += __shfl_xor(a2, 32);
    if (j == 0) h2[(size_t)node * 16 + cc] = a2;   // b2 added in final
}

// ---------------- fused agg2 + self-loop + b2 + log_softmax ----------------
// one 64-lane wave per node; lanes = (j 0..3, c 0..15), edges strided by 4
__global__ __launch_bounds__(256) void k_agg2_final(const int* __restrict__ offsets,
                                                    const int2* __restrict__ pack,
                                                    const float* __restrict__ dinv,
                                                    const float* __restrict__ h2,
                                                    const float* __restrict__ b2,
                                                    float* __restrict__ out) {
    const int tid = threadIdx.x;
    const int wave = tid >> 6;
    const int lane = tid & 63;
    const int node = blockIdx.x * 4 + wave;
    const int j = lane >> 4, c = lane & 15;

    float acc = 0.f;
    const int s0 = offsets[node], s1 = offsets[node + 1];
    for (int i = s0 + j; i < s1; i += 4) {
        int2 p = pack[i];
        acc = fmaf(h2[(size_t)p.x * 16 + c], __int_as_float(p.y), acc);
    }
    acc += __shfl_xor(acc, 16);
    acc += __shfl_xor(acc, 32);

    const float di = dinv[node];
    float z = acc + h2[(size_t)node * 16 + c] * di * di + b2[c];

    float m = z;
    #pragma unroll
    for (int off = 8; off >= 1; off >>= 1) m = fmaxf(m, __shfl_xor(m, off, 16));
    float ex = __expf(z - m);
    float ssum = ex;
    #pragma unroll
    for (int off = 8; off >= 1; off >>= 1) ssum += __shfl_xor(ssum, off, 16);
    if (j == 0) out[(size_t)node * 16 + c] = z - m - logf(ssum);
}

extern "C" void kernel_launch(void* const* d_in, const int* in_sizes, int n_in,
                              void* d_out, int out_size, void* d_ws, size_t ws_size,
                              hipStream_t stream) {
    const float* x  = (const float*)d_in[0];
    const int* ei   = (const int*)d_in[1];
    const float* W1 = (const float*)d_in[2];
    const float* b1 = (const float*)d_in[3];
    const float* W2 = (const float*)d_in[4];
    const float* b2 = (const float*)d_in[5];
    const int* src = ei;
    const int* dst = ei + N_EDGES;

    // workspace layout (all 4-byte elems; pack needs 8B alignment -> even int count before it)
    int*   degi    = (int*)d_ws;                        // N
    int*   cursor  = degi + N_NODES;                    // N      (memset degi+cursor together)
    float* dinv    = (float*)(cursor + N_NODES);        // N
    int*   offsets = (int*)(dinv + N_NODES);            // N+1
    int*   bsums   = offsets + N_NODES + 1;             // 511 (pads total to even)
    int2*  pack    = (int2*)(bsums + 511);              // E int2   (total ints before: 400512, even)
    float* h       = (float*)(pack + N_EDGES);          // N*64
    float* h2      = h + (size_t)N_NODES * 64;          // N*16
    float* out     = (float*)d_out;

    hipMemsetAsync(degi, 0, 2 * N_NODES * sizeof(int), stream);

    k_count_deg<<<(N_EDGES + 255) / 256, 256, 0, stream>>>(dst, degi);
    k_dinv<<<NBLK_NODES, 256, 0, stream>>>(degi, dinv);
    k_block_sum<<<NBLK_NODES, 256, 0, stream>>>(degi, bsums);
    k_scan_bsums<<<1, 512, 0, stream>>>(bsums, NBLK_NODES);
    k_scan_block<<<NBLK_NODES, 256, 0, stream>>>(degi, bsums, offsets);
    k_fill<<<(N_EDGES + 255) / 256, 256, 0, stream>>>(src, dst, dinv, offsets, cursor, pack);
    k_gemm1<<<(N_NODES + 63) / 64, 256, 0, stream>>>(x, W1, h);
    k_agg1_gemm2<<<N_NODES / 4, 256, 0, stream>>>(offsets, pack, dinv, h, b1, W2, h2);
    k_agg2_final<<<N_NODES / 4, 256, 0, stream>>>(offsets, pack, dinv, h2, b2, out);
}

// Round 3
// 389.447 us; speedup vs baseline: 1.7456x; 1.2816x over previous
//
#include <hip/hip_runtime.h>
#include <hip/hip_fp16.h>
#include <math.h>

#define N_NODES 100000
#define N_EDGES 1600000
#define FIN 256
#define NBLK_NODES 391   // ceil(100000/256)

// ---------------- degree (int) ----------------
__global__ __launch_bounds__(256) void k_count_deg(const int* __restrict__ dst, int* __restrict__ degi) {
    int e = blockIdx.x * 256 + threadIdx.x;
    if (e < N_EDGES) atomicAdd(&degi[dst[e]], 1);
}

__global__ __launch_bounds__(256) void k_dinv(const int* __restrict__ degi, float* __restrict__ dinv) {
    int i = blockIdx.x * 256 + threadIdx.x;
    if (i < N_NODES) dinv[i] = rsqrtf((float)degi[i] + 1.0f);  // +1 = self loop
}

// ---------------- CSR build: 2-level exclusive scan ----------------
__global__ __launch_bounds__(256) void k_block_sum(const int* __restrict__ degi, int* __restrict__ bsums) {
    __shared__ int sd[256];
    int tid = threadIdx.x;
    int i = blockIdx.x * 256 + tid;
    sd[tid] = (i < N_NODES) ? degi[i] : 0;
    __syncthreads();
    for (int s = 128; s > 0; s >>= 1) {
        if (tid < s) sd[tid] += sd[tid + s];
        __syncthreads();
    }
    if (tid == 0) bsums[blockIdx.x] = sd[0];
}

__global__ __launch_bounds__(512) void k_scan_bsums(int* __restrict__ bsums, int nb) {
    __shared__ int sd[512];
    int tid = threadIdx.x;
    int v = (tid < nb) ? bsums[tid] : 0;
    sd[tid] = v;
    __syncthreads();
    for (int off = 1; off < 512; off <<= 1) {
        int t = (tid >= off) ? sd[tid - off] : 0;
        __syncthreads();
        sd[tid] += t;
        __syncthreads();
    }
    if (tid < nb) bsums[tid] = sd[tid] - v;  // exclusive
}

__global__ __launch_bounds__(256) void k_scan_block(const int* __restrict__ degi,
                                                   const int* __restrict__ bsums,
                                                   int* __restrict__ offsets) {
    __shared__ int sd[256];
    int tid = threadIdx.x;
    int i = blockIdx.x * 256 + tid;
    int v = (i < N_NODES) ? degi[i] : 0;
    sd[tid] = v;
    __syncthreads();
    for (int off = 1; off < 256; off <<= 1) {
        int t = (tid >= off) ? sd[tid - off] : 0;
        __syncthreads();
        sd[tid] += t;
        __syncthreads();
    }
    if (i < N_NODES) offsets[i] = bsums[blockIdx.x] + sd[tid] - v;
    if (i == N_NODES - 1) offsets[N_NODES] = bsums[blockIdx.x] + sd[tid];
}

// ---------------- fill CSR slots: pack = {src, norm} ----------------
__global__ __launch_bounds__(256) void k_fill(const int* __restrict__ src, const int* __restrict__ dst,
                                              const float* __restrict__ dinv,
                                              const int* __restrict__ offsets, int* __restrict__ cursor,
                                              int2* __restrict__ pack) {
    int e = blockIdx.x * 256 + threadIdx.x;
    if (e >= N_EDGES) return;
    int s = src[e], d = dst[e];
    int pos = offsets[d] + atomicAdd(&cursor[d], 1);
    pack[pos] = make_int2(s, __float_as_int(dinv[s] * dinv[d]));
}

// ---------------- GEMM1: h = x @ W1  (N x 256 @ 256 x 64), fp16 out ----------------
__global__ __launch_bounds__(256) void k_gemm1(const float* __restrict__ x,
                                               const float* __restrict__ W1,
                                               __half* __restrict__ hh) {
    __shared__ float W1t[64][FIN];   // [c][swizzled k]
    __shared__ float xs[16][FIN];
    const int tid = threadIdx.x;
    const int c = tid & 63;
    const int rg = tid >> 6;
    const int cs = c & 7;

    for (int i = tid; i < FIN * 64; i += 256) {
        int k = i >> 6, cc = i & 63;
        int kq = k >> 2, j = k & 3;
        W1t[cc][(((kq ^ (cc & 7)) << 2) | j)] = W1[i];
    }

    const int row0 = blockIdx.x * 64;
    for (int rr = 0; rr < 64; rr += 16) {
        __syncthreads();
        for (int i = tid; i < 16 * 64; i += 256) {
            int r = i >> 6;
            int q = i & 63;
            int row = row0 + rr + r;
            float4 v = make_float4(0.f, 0.f, 0.f, 0.f);
            if (row < N_NODES) v = ((const float4*)x)[(size_t)row * 64 + q];
            *(float4*)&xs[r][q * 4] = v;
        }
        __syncthreads();

        float acc0 = 0.f, acc1 = 0.f, acc2 = 0.f, acc3 = 0.f;
        const float* w_row = &W1t[c][0];
        const float* x0r = &xs[rg * 4 + 0][0];
        const float* x1r = &xs[rg * 4 + 1][0];
        const float* x2r = &xs[rg * 4 + 2][0];
        const float* x3r = &xs[rg * 4 + 3][0];
        #pragma unroll 8
        for (int kq = 0; kq < 64; ++kq) {
            float4 w = *(const float4*)&w_row[(kq ^ cs) << 2];
            float4 a0 = *(const float4*)&x0r[kq << 2];
            float4 a1 = *(const float4*)&x1r[kq << 2];
            float4 a2 = *(const float4*)&x2r[kq << 2];
            float4 a3 = *(const float4*)&x3r[kq << 2];
            acc0 = fmaf(w.x, a0.x, fmaf(w.y, a0.y, fmaf(w.z, a0.z, fmaf(w.w, a0.w, acc0))));
            acc1 = fmaf(w.x, a1.x, fmaf(w.y, a1.y, fmaf(w.z, a1.z, fmaf(w.w, a1.w, acc1))));
            acc2 = fmaf(w.x, a2.x, fmaf(w.y, a2.y, fmaf(w.z, a2.z, fmaf(w.w, a2.w, acc2))));
            acc3 = fmaf(w.x, a3.x, fmaf(w.y, a3.y, fmaf(w.z, a3.z, fmaf(w.w, a3.w, acc3))));
        }
        // packed half2 stores: even-c lanes write (c, c+1)
        float o0 = __shfl_xor(acc0, 1);
        float o1 = __shfl_xor(acc1, 1);
        float o2 = __shfl_xor(acc2, 1);
        float o3 = __shfl_xor(acc3, 1);
        int row = row0 + rr + rg * 4;
        if ((c & 1) == 0) {
            if (row + 0 < N_NODES) *(__half2*)&hh[(size_t)(row + 0) * 64 + c] = __floats2half2_rn(acc0, o0);
            if (row + 1 < N_NODES) *(__half2*)&hh[(size_t)(row + 1) * 64 + c] = __floats2half2_rn(acc1, o1);
            if (row + 2 < N_NODES) *(__half2*)&hh[(size_t)(row + 2) * 64 + c] = __floats2half2_rn(acc2, o2);
            if (row + 3 < N_NODES) *(__half2*)&hh[(size_t)(row + 3) * 64 + c] = __floats2half2_rn(acc3, o3);
        }
    }
}

// ---------------- fused agg1 + self-loop + b1 + relu + GEMM2 (fp16 gather) ----------------
// one 64-lane wave per node; half-wave (32 lanes x half2) per edge, 4-deep unroll -> 8 gathers in flight
__global__ __launch_bounds__(256) void k_agg1_gemm2(const int* __restrict__ offsets,
                                                    const int2* __restrict__ pack,
                                                    const float* __restrict__ dinv,
                                                    const __half* __restrict__ hh,
                                                    const float* __restrict__ b1,
                                                    const float* __restrict__ W2,
                                                    __half* __restrict__ h2h) {
    __shared__ float W2s[64][17];
    __shared__ float h1s[4][64];
    const int tid = threadIdx.x;
    for (int i = tid; i < 64 * 16; i += 256) W2s[i >> 4][i & 15] = W2[i];
    __syncthreads();

    const int wave = tid >> 6;
    const int lane = tid & 63;
    const int node = blockIdx.x * 4 + wave;
    const int half_id = lane >> 5;
    const int l = lane & 31;          // channel pair index: channels 2l, 2l+1

    const int s0 = offsets[node], s1 = offsets[node + 1];
    float2 a0 = {0.f, 0.f}, a1 = {0.f, 0.f}, a2 = {0.f, 0.f}, a3 = {0.f, 0.f};
    int i = s0 + half_id;
    for (; i + 6 < s1; i += 8) {
        int2 p0 = pack[i], p1 = pack[i + 2], p2 = pack[i + 4], p3 = pack[i + 6];
        float2 f0 = __half22float2(*(const __half2*)(hh + (size_t)p0.x * 64 + 2 * l));
        float2 f1 = __half22float2(*(const __half2*)(hh + (size_t)p1.x * 64 + 2 * l));
        float2 f2 = __half22float2(*(const __half2*)(hh + (size_t)p2.x * 64 + 2 * l));
        float2 f3 = __half22float2(*(const __half2*)(hh + (size_t)p3.x * 64 + 2 * l));
        float w0 = __int_as_float(p0.y), w1 = __int_as_float(p1.y);
        float w2 = __int_as_float(p2.y), w3 = __int_as_float(p3.y);
        a0.x = fmaf(f0.x, w0, a0.x); a0.y = fmaf(f0.y, w0, a0.y);
        a1.x = fmaf(f1.x, w1, a1.x); a1.y = fmaf(f1.y, w1, a1.y);
        a2.x = fmaf(f2.x, w2, a2.x); a2.y = fmaf(f2.y, w2, a2.y);
        a3.x = fmaf(f3.x, w3, a3.x); a3.y = fmaf(f3.y, w3, a3.y);
    }
    for (; i < s1; i += 2) {
        int2 p = pack[i];
        float w = __int_as_float(p.y);
        float2 f = __half22float2(*(const __half2*)(hh + (size_t)p.x * 64 + 2 * l));
        a0.x = fmaf(f.x, w, a0.x); a0.y = fmaf(f.y, w, a0.y);
    }
    float2 acc;
    acc.x = (a0.x + a1.x) + (a2.x + a3.x);
    acc.y = (a0.y + a1.y) + (a2.y + a3.y);
    acc.x += __shfl_xor(acc.x, 32);
    acc.y += __shfl_xor(acc.y, 32);
    // all lanes now hold the full edge sum for channels (2l, 2l+1)
    if (half_id == 0) {
        const float di = dinv[node];
        const float dii = di * di;
        float2 sf = __half22float2(*(const __half2*)(hh + (size_t)node * 64 + 2 * l));
        acc.x = fmaf(sf.x, dii, acc.x) + b1[2 * l];
        acc.y = fmaf(sf.y, dii, acc.y) + b1[2 * l + 1];
        h1s[wave][2 * l]     = fmaxf(acc.x, 0.f);
        h1s[wave][2 * l + 1] = fmaxf(acc.y, 0.f);
    }
    // same-wave LDS write->read (lgkmcnt-ordered)
    const int j = lane >> 4, cc = lane & 15;
    float g = 0.f;
    #pragma unroll
    for (int t = 0; t < 16; ++t) {
        int k = j * 16 + t;
        g = fmaf(h1s[wave][k], W2s[k][cc], g);
    }
    g += __shfl_xor(g, 16);
    g += __shfl_xor(g, 32);
    // every lane holds h2[node][cc]; pack pairs, even-cc lanes of group j==0 store
    float go = __shfl_xor(g, 1);
    if (lane < 16 && (cc & 1) == 0) {
        *(__half2*)&h2h[(size_t)node * 16 + cc] = __floats2half2_rn(g, go);
    }
}

// ---------------- fused agg2 + self-loop + b2 + log_softmax (fp16 gather) ----------------
// one wave per node; 8 j-groups x half2 x unroll-2 -> 16 edges in flight
__global__ __launch_bounds__(256) void k_agg2_final(const int* __restrict__ offsets,
                                                    const int2* __restrict__ pack,
                                                    const float* __restrict__ dinv,
                                                    const __half* __restrict__ h2h,
                                                    const float* __restrict__ b2,
                                                    float* __restrict__ out) {
    const int tid = threadIdx.x;
    const int wave = tid >> 6;
    const int lane = tid & 63;
    const int node = blockIdx.x * 4 + wave;
    const int j = lane >> 3, cp = lane & 7;   // channels 2cp, 2cp+1

    const int s0 = offsets[node], s1 = offsets[node + 1];
    float2 a0 = {0.f, 0.f}, a1 = {0.f, 0.f};
    int i = s0 + j;
    for (; i + 8 < s1; i += 16) {
        int2 p0 = pack[i], p1 = pack[i + 8];
        float2 f0 = __half22float2(*(const __half2*)(h2h + (size_t)p0.x * 16 + 2 * cp));
        float2 f1 = __half22float2(*(const __half2*)(h2h + (size_t)p1.x * 16 + 2 * cp));
        float w0 = __int_as_float(p0.y), w1 = __int_as_float(p1.y);
        a0.x = fmaf(f0.x, w0, a0.x); a0.y = fmaf(f0.y, w0, a0.y);
        a1.x = fmaf(f1.x, w1, a1.x); a1.y = fmaf(f1.y, w1, a1.y);
    }
    for (; i < s1; i += 8) {
        int2 p = pack[i];
        float w = __int_as_float(p.y);
        float2 f = __half22float2(*(const __half2*)(h2h + (size_t)p.x * 16 + 2 * cp));
        a0.x = fmaf(f.x, w, a0.x); a0.y = fmaf(f.y, w, a0.y);
    }
    float2 z;
    z.x = a0.x + a1.x;
    z.y = a0.y + a1.y;
    z.x += __shfl_xor(z.x, 8);  z.y += __shfl_xor(z.y, 8);
    z.x += __shfl_xor(z.x, 16); z.y += __shfl_xor(z.y, 16);
    z.x += __shfl_xor(z.x, 32); z.y += __shfl_xor(z.y, 32);

    const float di = dinv[node];
    const float dii = di * di;
    float2 sf = __half22float2(*(const __half2*)(h2h + (size_t)node * 16 + 2 * cp));
    z.x = fmaf(sf.x, dii, z.x) + b2[2 * cp];
    z.y = fmaf(sf.y, dii, z.y) + b2[2 * cp + 1];

    float m = fmaxf(z.x, z.y);
    m = fmaxf(m, __shfl_xor(m, 1, 8));
    m = fmaxf(m, __shfl_xor(m, 2, 8));
    m = fmaxf(m, __shfl_xor(m, 4, 8));
    float ex = __expf(z.x - m), ey = __expf(z.y - m);
    float s = ex + ey;
    s += __shfl_xor(s, 1, 8);
    s += __shfl_xor(s, 2, 8);
    s += __shfl_xor(s, 4, 8);
    float ls = logf(s);
    if (j == 0) {
        float2 o;
        o.x = z.x - m - ls;
        o.y = z.y - m - ls;
        *(float2*)&out[(size_t)node * 16 + 2 * cp] = o;
    }
}

extern "C" void kernel_launch(void* const* d_in, const int* in_sizes, int n_in,
                              void* d_out, int out_size, void* d_ws, size_t ws_size,
                              hipStream_t stream) {
    const float* x  = (const float*)d_in[0];
    const int* ei   = (const int*)d_in[1];
    const float* W1 = (const float*)d_in[2];
    const float* b1 = (const float*)d_in[3];
    const float* W2 = (const float*)d_in[4];
    const float* b2 = (const float*)d_in[5];
    const int* src = ei;
    const int* dst = ei + N_EDGES;

    // workspace layout; ints before pack total 400512 (even) -> pack 8B aligned
    int*    degi    = (int*)d_ws;                        // N
    int*    cursor  = degi + N_NODES;                    // N
    float*  dinv    = (float*)(cursor + N_NODES);        // N
    int*    offsets = (int*)(dinv + N_NODES);            // N+1
    int*    bsums   = offsets + N_NODES + 1;             // 511
    int2*   pack    = (int2*)(bsums + 511);              // E int2
    __half* hh      = (__half*)(pack + N_EDGES);         // N*64 half
    __half* h2h     = hh + (size_t)N_NODES * 64;         // N*16 half
    float*  out     = (float*)d_out;

    hipMemsetAsync(degi, 0, 2 * N_NODES * sizeof(int), stream);

    k_count_deg<<<(N_EDGES + 255) / 256, 256, 0, stream>>>(dst, degi);
    k_dinv<<<NBLK_NODES, 256, 0, stream>>>(degi, dinv);
    k_block_sum<<<NBLK_NODES, 256, 0, stream>>>(degi, bsums);
    k_scan_bsums<<<1, 512, 0, stream>>>(bsums, NBLK_NODES);
    k_scan_block<<<NBLK_NODES, 256, 0, stream>>>(degi, bsums, offsets);
    k_fill<<<(N_EDGES + 255) / 256, 256, 0, stream>>>(src, dst, dinv, offsets, cursor, pack);
    k_gemm1<<<(N_NODES + 63) / 64, 256, 0, stream>>>(x, W1, hh);
    k_agg1_gemm2<<<N_NODES / 4, 256, 0, stream>>>(offsets, pack, dinv, hh, b1, W2, h2h);
    k_agg2_final<<<N_NODES / 4, 256, 0, stream>>>(offsets, pack, dinv, h2h, b2, out);
}

// Round 4
// 286.821 us; speedup vs baseline: 2.3702x; 1.3578x over previous
//
#include <hip/hip_runtime.h>
#include <hip/hip_fp16.h>
#include <math.h>

#define N_NODES 100000
#define N_EDGES 1600000
#define FIN 256
#define NBLK_NODES 391   // ceil(100000/256)

typedef _Float16 h8 __attribute__((ext_vector_type(8)));
typedef float f4 __attribute__((ext_vector_type(4)));

// ---------------- degree (int) ----------------
__global__ __launch_bounds__(256) void k_count_deg(const int* __restrict__ dst, int* __restrict__ degi) {
    int e = blockIdx.x * 256 + threadIdx.x;
    if (e < N_EDGES) atomicAdd(&degi[dst[e]], 1);
}

__global__ __launch_bounds__(256) void k_dinv(const int* __restrict__ degi, float* __restrict__ dinv) {
    int i = blockIdx.x * 256 + threadIdx.x;
    if (i < N_NODES) dinv[i] = rsqrtf((float)degi[i] + 1.0f);  // +1 = self loop
}

// ---------------- W1 -> f16 MFMA B-fragment layout ----------------
// frag elem i: j=i&7, lane=(i>>3)&63, ntile=(i>>9)&3, kstep=i>>11
// value = W1[kstep*32 + (lane>>4)*8 + j][ntile*16 + (lane&15)]
__global__ __launch_bounds__(256) void k_prepW1(const float* __restrict__ W1, _Float16* __restrict__ Bfrag) {
    int i = blockIdx.x * 256 + threadIdx.x;   // 0..16383
    int j = i & 7, lane = (i >> 3) & 63, nt = (i >> 9) & 3, ks = i >> 11;
    int k = ks * 32 + ((lane >> 4) << 3) + j;
    int c = nt * 16 + (lane & 15);
    Bfrag[i] = (_Float16)W1[k * 64 + c];
}

// ---------------- CSR build: 2-level exclusive scan ----------------
__global__ __launch_bounds__(256) void k_block_sum(const int* __restrict__ degi, int* __restrict__ bsums) {
    __shared__ int sd[256];
    int tid = threadIdx.x;
    int i = blockIdx.x * 256 + tid;
    sd[tid] = (i < N_NODES) ? degi[i] : 0;
    __syncthreads();
    for (int s = 128; s > 0; s >>= 1) {
        if (tid < s) sd[tid] += sd[tid + s];
        __syncthreads();
    }
    if (tid == 0) bsums[blockIdx.x] = sd[0];
}

__global__ __launch_bounds__(512) void k_scan_bsums(int* __restrict__ bsums, int nb) {
    __shared__ int sd[512];
    int tid = threadIdx.x;
    int v = (tid < nb) ? bsums[tid] : 0;
    sd[tid] = v;
    __syncthreads();
    for (int off = 1; off < 512; off <<= 1) {
        int t = (tid >= off) ? sd[tid - off] : 0;
        __syncthreads();
        sd[tid] += t;
        __syncthreads();
    }
    if (tid < nb) bsums[tid] = sd[tid] - v;  // exclusive
}

__global__ __launch_bounds__(256) void k_scan_block(const int* __restrict__ degi,
                                                   const int* __restrict__ bsums,
                                                   int* __restrict__ offsets) {
    __shared__ int sd[256];
    int tid = threadIdx.x;
    int i = blockIdx.x * 256 + tid;
    int v = (i < N_NODES) ? degi[i] : 0;
    sd[tid] = v;
    __syncthreads();
    for (int off = 1; off < 256; off <<= 1) {
        int t = (tid >= off) ? sd[tid - off] : 0;
        __syncthreads();
        sd[tid] += t;
        __syncthreads();
    }
    if (i < N_NODES) offsets[i] = bsums[blockIdx.x] + sd[tid] - v;
    if (i == N_NODES - 1) offsets[N_NODES] = bsums[blockIdx.x] + sd[tid];
}

// ---------------- fill CSR slots: pack = {src, norm} ----------------
__global__ __launch_bounds__(256) void k_fill(const int* __restrict__ src, const int* __restrict__ dst,
                                              const float* __restrict__ dinv,
                                              const int* __restrict__ offsets, int* __restrict__ cursor,
                                              int2* __restrict__ pack) {
    int e = blockIdx.x * 256 + threadIdx.x;
    if (e >= N_EDGES) return;
    int s = src[e], d = dst[e];
    int pos = offsets[d] + atomicAdd(&cursor[d], 1);
    pack[pos] = make_int2(s, __float_as_int(dinv[s] * dinv[d]));
}

// ---------------- GEMM1 via MFMA: h = x @ W1, f16 out ----------------
// 4 waves/block, wave owns 16 rows x 64 cols. No LDS. B frags from L2-hot global array.
__global__ __launch_bounds__(256) void k_gemm1(const float* __restrict__ x,
                                               const _Float16* __restrict__ Bfrag,
                                               __half* __restrict__ hh) {
    const int tid = threadIdx.x;
    const int wave = tid >> 6, lane = tid & 63;
    const int lrow = lane & 15;      // A row / D col
    const int lk = lane >> 4;        // k-chunk group 0..3 / D row-group
    const int row = blockIdx.x * 64 + wave * 16 + lrow;
    const int rowc = (row < N_NODES) ? row : (N_NODES - 1);
    const float* xp = x + (size_t)rowc * 256 + lk * 8;
    const h8* bp = (const h8*)Bfrag + lane;   // element ((ks*4+nt)*64 + lane)

    f4 acc0 = {0.f, 0.f, 0.f, 0.f};
    f4 acc1 = {0.f, 0.f, 0.f, 0.f};
    f4 acc2 = {0.f, 0.f, 0.f, 0.f};
    f4 acc3 = {0.f, 0.f, 0.f, 0.f};

    #pragma unroll 2
    for (int ks = 0; ks < 8; ++ks) {
        float4 a01 = *(const float4*)(xp + ks * 32);
        float4 a23 = *(const float4*)(xp + ks * 32 + 4);
        h8 af;
        af[0] = (_Float16)a01.x; af[1] = (_Float16)a01.y;
        af[2] = (_Float16)a01.z; af[3] = (_Float16)a01.w;
        af[4] = (_Float16)a23.x; af[5] = (_Float16)a23.y;
        af[6] = (_Float16)a23.z; af[7] = (_Float16)a23.w;
        h8 b0 = bp[(ks * 4 + 0) * 64];
        h8 b1 = bp[(ks * 4 + 1) * 64];
        h8 b2 = bp[(ks * 4 + 2) * 64];
        h8 b3 = bp[(ks * 4 + 3) * 64];
        acc0 = __builtin_amdgcn_mfma_f32_16x16x32_f16(af, b0, acc0, 0, 0, 0);
        acc1 = __builtin_amdgcn_mfma_f32_16x16x32_f16(af, b1, acc1, 0, 0, 0);
        acc2 = __builtin_amdgcn_mfma_f32_16x16x32_f16(af, b2, acc2, 0, 0, 0);
        acc3 = __builtin_amdgcn_mfma_f32_16x16x32_f16(af, b3, acc3, 0, 0, 0);
    }

    // D: col = lane&15, row = lk*4 + reg. Pack (c, c+1) via lane-pair shfl; even lanes store half2.
    const int orow0 = blockIdx.x * 64 + wave * 16 + lk * 4;
    const bool evlane = ((lane & 1) == 0);
#define STORE_TILE(ACC, NT) { \
    _Pragma("unroll") \
    for (int r = 0; r < 4; ++r) { \
        float v = ACC[r]; \
        float o = __shfl_xor(v, 1); \
        int orow = orow0 + r; \
        if (evlane && orow < N_NODES) \
            *(__half2*)&hh[(size_t)orow * 64 + (NT) * 16 + lrow] = __floats2half2_rn(v, o); \
    } }
    STORE_TILE(acc0, 0)
    STORE_TILE(acc1, 1)
    STORE_TILE(acc2, 2)
    STORE_TILE(acc3, 3)
#undef STORE_TILE
}

// ---------------- fused agg1 + self-loop + b1 + relu + GEMM2 (fp16 gather) ----------------
// one 64-lane wave per node; half-wave (32 lanes x half2) per edge, 4-deep unroll -> 8 gathers in flight
__global__ __launch_bounds__(256) void k_agg1_gemm2(const int* __restrict__ offsets,
                                                    const int2* __restrict__ pack,
                                                    const float* __restrict__ dinv,
                                                    const __half* __restrict__ hh,
                                                    const float* __restrict__ b1,
                                                    const float* __restrict__ W2,
                                                    __half* __restrict__ h2h) {
    __shared__ float W2s[64][17];
    __shared__ float h1s[4][64];
    const int tid = threadIdx.x;
    for (int i = tid; i < 64 * 16; i += 256) W2s[i >> 4][i & 15] = W2[i];
    __syncthreads();

    const int wave = tid >> 6;
    const int lane = tid & 63;
    const int node = blockIdx.x * 4 + wave;
    const int half_id = lane >> 5;
    const int l = lane & 31;          // channel pair index: channels 2l, 2l+1

    const int s0 = offsets[node], s1 = offsets[node + 1];
    float2 a0 = {0.f, 0.f}, a1 = {0.f, 0.f}, a2 = {0.f, 0.f}, a3 = {0.f, 0.f};
    int i = s0 + half_id;
    for (; i + 6 < s1; i += 8) {
        int2 p0 = pack[i], p1 = pack[i + 2], p2 = pack[i + 4], p3 = pack[i + 6];
        float2 f0 = __half22float2(*(const __half2*)(hh + (size_t)p0.x * 64 + 2 * l));
        float2 f1 = __half22float2(*(const __half2*)(hh + (size_t)p1.x * 64 + 2 * l));
        float2 f2 = __half22float2(*(const __half2*)(hh + (size_t)p2.x * 64 + 2 * l));
        float2 f3 = __half22float2(*(const __half2*)(hh + (size_t)p3.x * 64 + 2 * l));
        float w0 = __int_as_float(p0.y), w1 = __int_as_float(p1.y);
        float w2 = __int_as_float(p2.y), w3 = __int_as_float(p3.y);
        a0.x = fmaf(f0.x, w0, a0.x); a0.y = fmaf(f0.y, w0, a0.y);
        a1.x = fmaf(f1.x, w1, a1.x); a1.y = fmaf(f1.y, w1, a1.y);
        a2.x = fmaf(f2.x, w2, a2.x); a2.y = fmaf(f2.y, w2, a2.y);
        a3.x = fmaf(f3.x, w3, a3.x); a3.y = fmaf(f3.y, w3, a3.y);
    }
    for (; i < s1; i += 2) {
        int2 p = pack[i];
        float w = __int_as_float(p.y);
        float2 f = __half22float2(*(const __half2*)(hh + (size_t)p.x * 64 + 2 * l));
        a0.x = fmaf(f.x, w, a0.x); a0.y = fmaf(f.y, w, a0.y);
    }
    float2 acc;
    acc.x = (a0.x + a1.x) + (a2.x + a3.x);
    acc.y = (a0.y + a1.y) + (a2.y + a3.y);
    acc.x += __shfl_xor(acc.x, 32);
    acc.y += __shfl_xor(acc.y, 32);
    if (half_id == 0) {
        const float di = dinv[node];
        const float dii = di * di;
        float2 sf = __half22float2(*(const __half2*)(hh + (size_t)node * 64 + 2 * l));
        acc.x = fmaf(sf.x, dii, acc.x) + b1[2 * l];
        acc.y = fmaf(sf.y, dii, acc.y) + b1[2 * l + 1];
        h1s[wave][2 * l]     = fmaxf(acc.x, 0.f);
        h1s[wave][2 * l + 1] = fmaxf(acc.y, 0.f);
    }
    // same-wave LDS write->read (lgkmcnt-ordered)
    const int j = lane >> 4, cc = lane & 15;
    float g = 0.f;
    #pragma unroll
    for (int t = 0; t < 16; ++t) {
        int k = j * 16 + t;
        g = fmaf(h1s[wave][k], W2s[k][cc], g);
    }
    g += __shfl_xor(g, 16);
    g += __shfl_xor(g, 32);
    float go = __shfl_xor(g, 1);
    if (lane < 16 && (cc & 1) == 0) {
        *(__half2*)&h2h[(size_t)node * 16 + cc] = __floats2half2_rn(g, go);
    }
}

// ---------------- fused agg2 + self-loop + b2 + log_softmax (fp16 gather) ----------------
__global__ __launch_bounds__(256) void k_agg2_final(const int* __restrict__ offsets,
                                                    const int2* __restrict__ pack,
                                                    const float* __restrict__ dinv,
                                                    const __half* __restrict__ h2h,
                                                    const float* __restrict__ b2,
                                                    float* __restrict__ out) {
    const int tid = threadIdx.x;
    const int wave = tid >> 6;
    const int lane = tid & 63;
    const int node = blockIdx.x * 4 + wave;
    const int j = lane >> 3, cp = lane & 7;   // channels 2cp, 2cp+1

    const int s0 = offsets[node], s1 = offsets[node + 1];
    float2 a0 = {0.f, 0.f}, a1 = {0.f, 0.f};
    int i = s0 + j;
    for (; i + 8 < s1; i += 16) {
        int2 p0 = pack[i], p1 = pack[i + 8];
        float2 f0 = __half22float2(*(const __half2*)(h2h + (size_t)p0.x * 16 + 2 * cp));
        float2 f1 = __half22float2(*(const __half2*)(h2h + (size_t)p1.x * 16 + 2 * cp));
        float w0 = __int_as_float(p0.y), w1 = __int_as_float(p1.y);
        a0.x = fmaf(f0.x, w0, a0.x); a0.y = fmaf(f0.y, w0, a0.y);
        a1.x = fmaf(f1.x, w1, a1.x); a1.y = fmaf(f1.y, w1, a1.y);
    }
    for (; i < s1; i += 8) {
        int2 p = pack[i];
        float w = __int_as_float(p.y);
        float2 f = __half22float2(*(const __half2*)(h2h + (size_t)p.x * 16 + 2 * cp));
        a0.x = fmaf(f.x, w, a0.x); a0.y = fmaf(f.y, w, a0.y);
    }
    float2 z;
    z.x = a0.x + a1.x;
    z.y = a0.y + a1.y;
    z.x += __shfl_xor(z.x, 8);  z.y += __shfl_xor(z.y, 8);
    z.x += __shfl_xor(z.x, 16); z.y += __shfl_xor(z.y, 16);
    z.x += __shfl_xor(z.x, 32); z.y += __shfl_xor(z.y, 32);

    const float di = dinv[node];
    const float dii = di * di;
    float2 sf = __half22float2(*(const __half2*)(h2h + (size_t)node * 16 + 2 * cp));
    z.x = fmaf(sf.x, dii, z.x) + b2[2 * cp];
    z.y = fmaf(sf.y, dii, z.y) + b2[2 * cp + 1];

    float m = fmaxf(z.x, z.y);
    m = fmaxf(m, __shfl_xor(m, 1, 8));
    m = fmaxf(m, __shfl_xor(m, 2, 8));
    m = fmaxf(m, __shfl_xor(m, 4, 8));
    float ex = __expf(z.x - m), ey = __expf(z.y - m);
    float s = ex + ey;
    s += __shfl_xor(s, 1, 8);
    s += __shfl_xor(s, 2, 8);
    s += __shfl_xor(s, 4, 8);
    float ls = logf(s);
    if (j == 0) {
        float2 o;
        o.x = z.x - m - ls;
        o.y = z.y - m - ls;
        *(float2*)&out[(size_t)node * 16 + 2 * cp] = o;
    }
}

extern "C" void kernel_launch(void* const* d_in, const int* in_sizes, int n_in,
                              void* d_out, int out_size, void* d_ws, size_t ws_size,
                              hipStream_t stream) {
    const float* x  = (const float*)d_in[0];
    const int* ei   = (const int*)d_in[1];
    const float* W1 = (const float*)d_in[2];
    const float* b1 = (const float*)d_in[3];
    const float* W2 = (const float*)d_in[4];
    const float* b2 = (const float*)d_in[5];
    const int* src = ei;
    const int* dst = ei + N_EDGES;

    // workspace layout: Bfrag first (16B aligned), then ints (400612, even), pack 8B-aligned
    _Float16* Bfrag = (_Float16*)d_ws;                   // 16384 halves (32 KB)
    int*    degi    = (int*)(Bfrag + 16384);             // N
    int*    cursor  = degi + N_NODES;                    // N
    float*  dinv    = (float*)(cursor + N_NODES);        // N
    int*    offsets = (int*)(dinv + N_NODES);            // N+1
    int*    bsums   = offsets + N_NODES + 1;             // 511
    int2*   pack    = (int2*)(bsums + 511);              // E int2
    __half* hh      = (__half*)(pack + N_EDGES);         // N*64 half
    __half* h2h     = hh + (size_t)N_NODES * 64;         // N*16 half
    float*  out     = (float*)d_out;

    hipMemsetAsync(degi, 0, 2 * N_NODES * sizeof(int), stream);

    k_count_deg<<<(N_EDGES + 255) / 256, 256, 0, stream>>>(dst, degi);
    k_dinv<<<NBLK_NODES, 256, 0, stream>>>(degi, dinv);
    k_prepW1<<<64, 256, 0, stream>>>(W1, Bfrag);
    k_block_sum<<<NBLK_NODES, 256, 0, stream>>>(degi, bsums);
    k_scan_bsums<<<1, 512, 0, stream>>>(bsums, NBLK_NODES);
    k_scan_block<<<NBLK_NODES, 256, 0, stream>>>(degi, bsums, offsets);
    k_fill<<<(N_EDGES + 255) / 256, 256, 0, stream>>>(src, dst, dinv, offsets, cursor, pack);
    k_gemm1<<<(N_NODES + 63) / 64, 256, 0, stream>>>(x, Bfrag, hh);
    k_agg1_gemm2<<<N_NODES / 4, 256, 0, stream>>>(offsets, pack, dinv, hh, b1, W2, h2h);
    k_agg2_final<<<N_NODES / 4, 256, 0, stream>>>(offsets, pack, dinv, h2h, b2, out);
}